// Round 19
// baseline (53.268 us; speedup 1.0000x reference)
//
#include <hip/hip_runtime.h>

// OIM unsupervised loss, MI355X/gfx950 — round 19.
// R14/R18 per-tile code kept verbatim; execution model = persistent-lite with
// STATIC schedule: grid 768 (3 blocks/CU, ONE dispatch generation), block b
// serially runs tiles {b, b+768, b+1536, b+2304<2560}. Stride 768 preserves
// xcd AND rb -> each block keeps its A-panel/XCD; cb hops by 24 in-slice
// (locality >= R14's static swizzle; fixes R9's dynamic-queue mistake).
// One extra __syncthreads per tile protects rl_s reuse.

#define BT 4096
#define NPID 5000
#define FDIM 256
#define NCHUNK 8         // FDIM / 32
#define BPROWS 10240
#define SIDE 5120
#define SCALE2 43.2808512266689f   // 30*log2(e)
#define LN2 0.6931471805599453f
#define BIGVAL 0x7FFFFFFF
#define NPAD 120.0f                // pad columns per side, each exp2(0)=1
#define FXS 67108864.0             // 2^26 fixed-point scale

typedef __attribute__((ext_vector_type(8))) _Float16 half8;
typedef __attribute__((ext_vector_type(4))) _Float16 half4;
typedef __attribute__((ext_vector_type(4))) float f32x4;

#if __has_builtin(__builtin_amdgcn_exp2f)
#define EXP2R(x) __builtin_amdgcn_exp2f(x)
#else
#define EXP2R(x) exp2f(x)
#endif

// 16B-unit index of (row, oct) in 16x16x32 fragment-linear layout.
// frag-block = 16 rows x 32 k = 1KB; lane = (row&15) + 16*(k>>3).
__device__ __forceinline__ size_t frag_unit(int row, int oct) {
  int c  = oct >> 2;   // 32-wide k-chunk (0..7)
  int ko = oct & 3;    // 8-wide oct within chunk
  return ((size_t)(row >> 4) * NCHUNK + c) * 64 + (row & 15) + (ko << 4);
}

// prep: blockIdx ranges -> convert_B (2 octs/thread) | meta | zero
__global__ __launch_bounds__(256) void prep(const float* __restrict__ inputs,
                                            const int* __restrict__ roi,
                                            const float* __restrict__ lut,
                                            const float* __restrict__ reid,
                                            const int* __restrict__ rlab,
                                            _Float16* __restrict__ Ap,
                                            _Float16* __restrict__ Bp,
                                            int* __restrict__ g,
                                            float* __restrict__ w2f, float* __restrict__ v1f,
                                            float* __restrict__ fcv, float* __restrict__ target,
                                            int* __restrict__ poscnt,
                                            unsigned long long* __restrict__ ctrl) {
  const int b = blockIdx.x, tid = threadIdx.x;
  if (b < 640) {                       // ---- convert_B: 2 octs per thread ----
    int idx = b * 256 + tid;           // 163840 = 10240*16
    int row = idx >> 4, p = idx & 15;  // octs {2p, 2p+1} = cols 16p..16p+15
    const float* src = nullptr;
    if (row < NPID) src = lut + (size_t)row * FDIM + p * 16;
    else if (row >= SIDE && row < SIDE + NPID) src = reid + (size_t)(row - SIDE) * FDIM + p * 16;
    half8 o0, o1;
    if (src) {
      const float4* s4 = (const float4*)src;
      float4 f0 = s4[0], f1 = s4[1], f2 = s4[2], f3 = s4[3];
      float fv[16] = {f0.x, f0.y, f0.z, f0.w, f1.x, f1.y, f1.z, f1.w,
                      f2.x, f2.y, f2.z, f2.w, f3.x, f3.y, f3.z, f3.w};
#pragma unroll
      for (int j = 0; j < 8; ++j) { o0[j] = (_Float16)fv[j]; o1[j] = (_Float16)fv[8 + j]; }
    } else {
#pragma unroll
      for (int j = 0; j < 8; ++j) { o0[j] = (_Float16)0.f; o1[j] = (_Float16)0.f; }
    }
    *(half8*)(Bp + frag_unit(row, 2 * p) * 8) = o0;
    *(half8*)(Bp + frag_unit(row, 2 * p + 1) * 8) = o1;
  } else if (b < 1664) {               // ---- meta: flags, fc, target, conv_A ----
    int gt = (b - 640) * 256 + tid;    // 262144 = 4096*64
    int row = gt >> 6, lane = gt & 63;
    int t = roi[row] - 1;
    bool valid = t >= 0;
    int label = t > 0 ? t : 0;
    int gg = rlab[label];
    int lrv = gg > 0 ? gg : 0;
    const float4* xv = (const float4*)(inputs + (size_t)row * FDIM);
    const float4* lv = (const float4*)(lut + (size_t)label * FDIM);
    const float4* rv = (const float4*)(reid + (size_t)lrv * FDIM);
    float4 a = xv[lane], bb = lv[lane], cv = rv[lane];
    half4 hv;
    hv[0] = (_Float16)(a.x * SCALE2);
    hv[1] = (_Float16)(a.y * SCALE2);
    hv[2] = (_Float16)(a.z * SCALE2);
    hv[3] = (_Float16)(a.w * SCALE2);
    *(half4*)(Ap + frag_unit(row, lane >> 1) * 8 + (lane & 1) * 4) = hv;
    float dx = bb.x - a.x, dy = bb.y - a.y, dz = bb.z - a.z, dw = bb.w - a.w;
    float s = dx * dx + dy * dy + dz * dz + dw * dw;
    float t2 = a.x * cv.x + a.y * cv.y + a.z * cv.z + a.w * cv.w;
#pragma unroll
    for (int d = 1; d < 64; d <<= 1) {
      s  += __shfl_xor(s, d, 64);
      t2 += __shfl_xor(t2, d, 64);
    }
    if (lane == 0) {
      g[row]      = gg;
      w2f[row]    = (valid && gg >= 0) ? 1.0f : 0.0f;
      v1f[row]    = valid ? 1.0f : 0.0f;
      fcv[row]    = valid ? s : 0.0f;
      target[row] = SCALE2 * t2;        // f32-exact CE target, base-2 scaled
    }
  } else {                             // ---- zeroing ----
    int idx = (b - 1664) * 256 + tid;  // 4096
    poscnt[idx] = 0;
    if (b == 1664 && tid < 8) ctrl[tid] = 0ULL;
  }
}

__global__ __launch_bounds__(256, 3) void gemm_main(const _Float16* __restrict__ Ap,
                                                    const _Float16* __restrict__ Bp,
                                                    const int* __restrict__ rlab,
                                                    const int* __restrict__ g,
                                                    float* __restrict__ partials,
                                                    float* __restrict__ posbuf,
                                                    int* __restrict__ poscnt) {
  // LDS: 2 x 16KB K-tile buffers (A 8 frag + B 8 frag each) + 512B rl_s
  __shared__ unsigned short lds[16640] __attribute__((aligned(16)));
  int* rl_s = (int*)&lds[16384];
  const int bid = blockIdx.x;            // 0..767, persistent-lite
  const int tid = threadIdx.x;
  const int l = tid & 63;
  const int w = tid >> 6;
  const int wr = w >> 1, wc = w & 1;
  const int rlane = l & 15;
  const int colg = l >> 4;               // 0..3
  const float NINF = -__builtin_inff();

  for (int it = 0; it < 4; ++it) {       // static schedule: tiles bid + 768*it
    const int tile = bid + it * 768;
    if (tile >= 2560) break;             // block-uniform
    // XCD-bijective decode (identical to R14's swizzle): stride 768 keeps
    // xcd and rb fixed per block; cb hops by 24 within the XCD slice.
    const int xcd = tile & 7;
    const int i   = tile >> 3;
    const int cb  = i >> 2;              // 0..79 (0..39 inst, 40..79 reid)
    const int rb  = xcd * 4 + (i & 3);   // 0..31, constant per block
    const bool inst = cb < 40;
    const int cbl = inst ? cb : cb - 40;

    __syncthreads();                     // prev tile's epilogue done with rl_s
    // ---- prologue: rl_s + inst row-keys (latency hidden under K-loop) ----
    if (tid < 128) {
      int scol = cbl * 128 + tid;
      rl_s[tid] = (inst && scol < NPID) ? rlab[scol] : BIGVAL;
    }
    const int rowb = rb * 128 + wr * 64 + rlane;
    int key[4];
#pragma unroll
    for (int nr = 0; nr < 4; ++nr)
      key[nr] = inst ? g[rowb + nr * 16] : BIGVAL;

    f32x4 acc[4][4];
#pragma unroll
    for (int mi = 0; mi < 4; ++mi)
#pragma unroll
      for (int ni = 0; ni < 4; ++ni) acc[mi][ni] = (f32x4){0.f, 0.f, 0.f, 0.f};

    // stage K-chunk t (32-wide) into buffer b: 16 frag-blocks, 4/wave.
    auto stage = [&](int t, int b) {
#pragma unroll
      for (int q = 0; q < 4; ++q) {
        const int f = w * 4 + q;           // 0..15
        const bool isA = f < 8;
        const int grp = f & 7;
        const int gidx = (isA ? rb * 8 : cb * 8) + grp;
        const _Float16* src = (isA ? Ap : Bp) + (((size_t)gidx * NCHUNK + t) << 9) + l * 8;
        unsigned short* dst = &lds[b * 8192 + (isA ? 0 : 4096) + grp * 512];
        __builtin_amdgcn_global_load_lds((const __attribute__((address_space(1))) unsigned int*)src,
                                         (__attribute__((address_space(3))) unsigned int*)dst,
                                         16, 0, 0);
      }
    };

    stage(0, 0);
    __syncthreads();                       // drain prologue stage + rl_s ordering
    int cur = 0;
#pragma unroll
    for (int t = 0; t < 8; ++t) {
      if (t < 7) stage(t + 1, cur ^ 1);    // issue-early: overlaps compute below
      half8 cf[4], rf[4];
#pragma unroll
      for (int mc = 0; mc < 4; ++mc)       // B frags
        cf[mc] = *(const half8*)&lds[cur * 8192 + 4096 + (wc * 4 + mc) * 512 + l * 8];
#pragma unroll
      for (int nr = 0; nr < 4; ++nr)       // A frags
        rf[nr] = *(const half8*)&lds[cur * 8192 + (wr * 4 + nr) * 512 + l * 8];
#pragma unroll
      for (int mc = 0; mc < 4; ++mc)
#pragma unroll
        for (int nr = 0; nr < 4; ++nr)
          acc[mc][nr] = __builtin_amdgcn_mfma_f32_16x16x32_f16(cf[mc], rf[nr], acc[mc][nr], 0, 0, 0);
      asm volatile("s_waitcnt vmcnt(0)" ::: "memory");  // next-tile loads landed
      asm volatile("s_barrier" ::: "memory");           // + all waves done reading cur
      cur ^= 1;
    }

    // ---- epilogue: unconditional exp2 sums (pads = +1 each, fixed in combine);
    //      inst side: positive exclusion via cndmask + rare posbuf branch ----
    const int chunk = (inst ? 0 : 80) + cbl * 2 + wc;

    if (inst) {
      int4 rlv[4];
#pragma unroll
      for (int mc = 0; mc < 4; ++mc)          // broadcast reads, conflict-free
        rlv[mc] = *(const int4*)&rl_s[wc * 64 + mc * 16 + colg * 4];
#pragma unroll
      for (int nr = 0; nr < 4; ++nr) {
        const int row = rowb + nr * 16;
        const int kv = key[nr];
        float s = 0.f;
        int pmask = 0;
#pragma unroll
        for (int mc = 0; mc < 4; ++mc)
#pragma unroll
          for (int reg = 0; reg < 4; ++reg) {
            float x2 = acc[mc][nr][reg];       // already 30*log2e scaled
            int rl = ((const int*)&rlv[mc])[reg];
            bool pos = (rl == kv);
            pmask |= pos ? (1 << (mc * 4 + reg)) : 0;
            s += EXP2R(pos ? NINF : x2);       // exp2(-inf)=0
          }
        if (__builtin_expect(pmask != 0, 0)) {
#pragma unroll
          for (int mc = 0; mc < 4; ++mc)
#pragma unroll
            for (int reg = 0; reg < 4; ++reg)
              if (pmask & (1 << (mc * 4 + reg))) {
                int idx = atomicAdd(&poscnt[row], 1);
                if (idx < 16) posbuf[row * 16 + idx] = acc[mc][nr][reg];
              }
        }
        s += __shfl_xor(s, 16, 64);
        s += __shfl_xor(s, 32, 64);
        if (colg == 0) partials[(size_t)chunk * BT + row] = s;
      }
    } else {
#pragma unroll
      for (int nr = 0; nr < 4; ++nr) {
        const int row = rowb + nr * 16;
        float s = 0.f;
#pragma unroll
        for (int mc = 0; mc < 4; ++mc)
#pragma unroll
          for (int reg = 0; reg < 4; ++reg)
            s += EXP2R(acc[mc][nr][reg]);
        s += __shfl_xor(s, 16, 64);
        s += __shfl_xor(s, 32, 64);
        if (colg == 0) partials[(size_t)chunk * BT + row] = s;
      }
    }
  }
}

// combine + finalize: per-row losses (pad-corrected sums), block-reduce,
// int64 fixed-point atomics (deterministic), last block writes out[0].
__global__ __launch_bounds__(256) void combine(const float* __restrict__ partials,
                                               const float* __restrict__ posbuf,
                                               const int* __restrict__ poscnt,
                                               const float* __restrict__ target,
                                               const float* __restrict__ w2f,
                                               const float* __restrict__ v1f,
                                               const float* __restrict__ fcv,
                                               unsigned long long* __restrict__ ctrl,
                                               float* __restrict__ out) {
  const int tid = threadIdx.x;
  const int row = blockIdx.x * 256 + tid;
  float S = 0.f;
  for (int i = 0; i < 80; ++i) S += partials[(size_t)i * BT + row];
  S -= NPAD;                                // remove exact pad contribution
  float lse2n = __log2f(S);                 // base-2 lse of negatives
  int cnt = poscnt[row];
  int cc = cnt < 16 ? cnt : 16;
  float sum = 0.f;
  for (int j = 0; j < cc; ++j) {
    float d = LN2 * (lse2n - posbuf[row * 16 + j]);
    sum += (d > 60.f) ? d : log1pf(__expf(d));
  }
  float w2 = w2f[row];
  float v[5];
  v[0] = fcv[row];
  v[1] = v1f[row];
  v[2] = w2;
  v[3] = w2 * (sum / fmaxf((float)cnt, 1.0f));
  float S2 = 0.f;
  for (int i = 80; i < 160; ++i) S2 += partials[(size_t)i * BT + row];
  S2 -= NPAD;
  v[4] = w2 * LN2 * (__log2f(S2) - target[row]);

#pragma unroll
  for (int k = 0; k < 5; ++k)
#pragma unroll
    for (int d = 1; d < 64; d <<= 1) v[k] += __shfl_xor(v[k], d, 64);
  __shared__ float red[4][5];
  int lane = tid & 63, wv = tid >> 6;
  if (lane == 0)
#pragma unroll
    for (int k = 0; k < 5; ++k) red[wv][k] = v[k];
  __syncthreads();
  if (tid == 0) {
#pragma unroll
    for (int k = 0; k < 5; ++k) {
      double bs = (double)red[0][k] + red[1][k] + red[2][k] + red[3][k];
      long long q = (long long)(bs * FXS + 0.5);
      atomicAdd(&ctrl[k], (unsigned long long)q);
    }
    __threadfence();
    unsigned int prev = atomicAdd((unsigned int*)&ctrl[6], 1u);
    if (prev == (unsigned int)(gridDim.x - 1)) {
      double a[5];
#pragma unroll
      for (int k = 0; k < 5; ++k)
        a[k] = (double)(long long)atomicAdd(&ctrl[k], 0ULL) / FXS;
      double n1 = a[1] > 1.0 ? a[1] : 1.0;
      double n2 = a[2] > 1.0 ? a[2] : 1.0;
      out[0] = (float)(a[0] / (n1 * (double)FDIM) + a[4] / n2 + a[3] / n2);
    }
  }
}

extern "C" void kernel_launch(void* const* d_in, const int* in_sizes, int n_in,
                              void* d_out, int out_size, void* d_ws, size_t ws_size,
                              hipStream_t stream) {
  const float* inputs = (const float*)d_in[0];
  const int*   roi    = (const int*)d_in[1];
  const float* lut    = (const float*)d_in[2];
  const float* reid   = (const float*)d_in[3];
  const int*   rlab   = (const int*)d_in[4];
  float* out = (float*)d_out;

  char* w = (char*)d_ws;
  _Float16* Ap    = (_Float16*)(w);                  // 2,097,152 B
  _Float16* Bp    = (_Float16*)(w + 2097152);        // 5,242,880 B  -> 7,340,032
  float* partials = (float*)(w + 7340032);           // 2,621,440 B  -> 9,961,472
  float* posbuf   = (float*)(w + 9961472);           // 262,144 B    -> 10,223,616
  int*   poscnt   = (int*)(w + 10223616);            // 16,384 B     -> 10,240,000
  float* target   = (float*)(w + 10240000);          // 16,384 B     -> 10,256,384
  int*   g        = (int*)(w + 10256384);            // 16,384 B     -> 10,272,768
  float* w2f      = (float*)(w + 10272768);          // 16,384 B     -> 10,289,152
  float* v1f      = (float*)(w + 10289152);          // 16,384 B     -> 10,305,536
  float* fcv      = (float*)(w + 10305536);          // 16,384 B     -> 10,321,920
  unsigned long long* ctrl = (unsigned long long*)(w + 10321920);  // 64 B

  prep<<<1680, 256, 0, stream>>>(inputs, roi, lut, reid, rlab, Ap, Bp,
                                 g, w2f, v1f, fcv, target, poscnt, ctrl);
  gemm_main<<<768, 256, 0, stream>>>(Ap, Bp, rlab, g, partials, posbuf, poscnt);
  combine<<<BT / 256, 256, 0, stream>>>(partials, posbuf, poscnt, target,
                                        w2f, v1f, fcv, ctrl, out);
}

// Round 20
// 52.194 us; speedup vs baseline: 1.0206x; 1.0206x over previous
//
#include <hip/hip_runtime.h>

// OIM unsupervised loss, MI355X/gfx950 — FINAL (= round 14, best measured
// 52.48us over 19 rounds of A/B). f16 K=256 MFMA GEMM (logits = 30*cosine;
// f16 quantization error ~1e-4 on the loss, measured absmax 0.0), m97-family
// 128x128 tile, 4 waves, issue-early double-buffered BK=32 K-loop,
// global_load_lds w=16, fragment-linear operands, XCD-bijective swizzle,
// branch-free exp2 epilogue (pads counted then subtracted exactly),
// deterministic int64 fixed-point finalize.
// Rejected by measurement: bf16 hi/lo K=768 (3x work), 256^2 tiles (latency-
// bound at K=256), counted-vmcnt 3-buf (regime gate), persistent blocks
// (L2 locality / neutral), occupancy 4-5 blocks (neutral / spills),
// in-kernel combine fusion (regalloc perturbation).

#define BT 4096
#define NPID 5000
#define FDIM 256
#define NCHUNK 8         // FDIM / 32
#define BPROWS 10240
#define SIDE 5120
#define SCALE2 43.2808512266689f   // 30*log2(e)
#define LN2 0.6931471805599453f
#define BIGVAL 0x7FFFFFFF
#define NPAD 120.0f                // pad columns per side, each exp2(0)=1
#define FXS 67108864.0             // 2^26 fixed-point scale

typedef __attribute__((ext_vector_type(8))) _Float16 half8;
typedef __attribute__((ext_vector_type(4))) _Float16 half4;
typedef __attribute__((ext_vector_type(4))) float f32x4;

#if __has_builtin(__builtin_amdgcn_exp2f)
#define EXP2R(x) __builtin_amdgcn_exp2f(x)
#else
#define EXP2R(x) exp2f(x)
#endif

// 16B-unit index of (row, oct) in 16x16x32 fragment-linear layout.
// frag-block = 16 rows x 32 k = 1KB; lane = (row&15) + 16*(k>>3).
__device__ __forceinline__ size_t frag_unit(int row, int oct) {
  int c  = oct >> 2;   // 32-wide k-chunk (0..7)
  int ko = oct & 3;    // 8-wide oct within chunk
  return ((size_t)(row >> 4) * NCHUNK + c) * 64 + (row & 15) + (ko << 4);
}

// prep: blockIdx ranges -> convert_B | meta (flags+fc+target+convert_A) | zero
__global__ __launch_bounds__(256) void prep(const float* __restrict__ inputs,
                                            const int* __restrict__ roi,
                                            const float* __restrict__ lut,
                                            const float* __restrict__ reid,
                                            const int* __restrict__ rlab,
                                            _Float16* __restrict__ Ap,
                                            _Float16* __restrict__ Bp,
                                            int* __restrict__ g,
                                            float* __restrict__ w2f, float* __restrict__ v1f,
                                            float* __restrict__ fcv, float* __restrict__ target,
                                            int* __restrict__ poscnt,
                                            unsigned long long* __restrict__ ctrl) {
  const int b = blockIdx.x, tid = threadIdx.x;
  if (b < 1280) {                      // ---- convert_B ----
    int idx = b * 256 + tid;           // 327680 = 10240*32
    int row = idx >> 5, oct = idx & 31;
    const float* src = nullptr;
    if (row < NPID) src = lut + (size_t)row * FDIM + oct * 8;
    else if (row >= SIDE && row < SIDE + NPID) src = reid + (size_t)(row - SIDE) * FDIM + oct * 8;
    half8 ov;
    if (src) {
      const float4* s4 = (const float4*)src;
      float4 f0 = s4[0], f1 = s4[1];
      float fv[8] = {f0.x, f0.y, f0.z, f0.w, f1.x, f1.y, f1.z, f1.w};
#pragma unroll
      for (int j = 0; j < 8; ++j) ov[j] = (_Float16)fv[j];
    } else {
#pragma unroll
      for (int j = 0; j < 8; ++j) ov[j] = (_Float16)0.f;
    }
    *(half8*)(Bp + frag_unit(row, oct) * 8) = ov;
  } else if (b < 2304) {               // ---- meta: flags, fc, target, conv_A ----
    int gt = (b - 1280) * 256 + tid;   // 262144 = 4096*64
    int row = gt >> 6, lane = gt & 63;
    int t = roi[row] - 1;
    bool valid = t >= 0;
    int label = t > 0 ? t : 0;
    int gg = rlab[label];
    int lrv = gg > 0 ? gg : 0;
    const float4* xv = (const float4*)(inputs + (size_t)row * FDIM);
    const float4* lv = (const float4*)(lut + (size_t)label * FDIM);
    const float4* rv = (const float4*)(reid + (size_t)lrv * FDIM);
    float4 a = xv[lane], bb = lv[lane], cv = rv[lane];
    // A-conversion: lane owns cols 4*lane..4*lane+3 -> oct = lane>>1,
    // half-offset (lane&1)*4 within the 16B unit.
    half4 hv;
    hv[0] = (_Float16)(a.x * SCALE2);
    hv[1] = (_Float16)(a.y * SCALE2);
    hv[2] = (_Float16)(a.z * SCALE2);
    hv[3] = (_Float16)(a.w * SCALE2);
    *(half4*)(Ap + frag_unit(row, lane >> 1) * 8 + (lane & 1) * 4) = hv;
    float dx = bb.x - a.x, dy = bb.y - a.y, dz = bb.z - a.z, dw = bb.w - a.w;
    float s = dx * dx + dy * dy + dz * dz + dw * dw;
    float t2 = a.x * cv.x + a.y * cv.y + a.z * cv.z + a.w * cv.w;
#pragma unroll
    for (int d = 1; d < 64; d <<= 1) {
      s  += __shfl_xor(s, d, 64);
      t2 += __shfl_xor(t2, d, 64);
    }
    if (lane == 0) {
      g[row]      = gg;
      w2f[row]    = (valid && gg >= 0) ? 1.0f : 0.0f;
      v1f[row]    = valid ? 1.0f : 0.0f;
      fcv[row]    = valid ? s : 0.0f;
      target[row] = SCALE2 * t2;        // f32-exact CE target, base-2 scaled
    }
  } else {                             // ---- zeroing ----
    int idx = (b - 2304) * 256 + tid;  // 4096
    poscnt[idx] = 0;
    if (b == 2304 && tid < 8) ctrl[tid] = 0ULL;
  }
}

__global__ __launch_bounds__(256, 3) void gemm_main(const _Float16* __restrict__ Ap,
                                                    const _Float16* __restrict__ Bp,
                                                    const int* __restrict__ rlab,
                                                    const int* __restrict__ g,
                                                    float* __restrict__ partials,
                                                    float* __restrict__ posbuf,
                                                    int* __restrict__ poscnt) {
  // LDS: 2 x 16KB K-tile buffers (A 8 frag + B 8 frag each) + 512B rl_s
  __shared__ unsigned short lds[16640] __attribute__((aligned(16)));
  int* rl_s = (int*)&lds[16384];
  // XCD-bijective, rb-fast swizzle: 2560 = 8 xcd * (80 cb * 4 rbl).
  const int bid = blockIdx.x;
  const int xcd = bid & 7;
  const int i   = bid >> 3;
  const int cb  = i >> 2;              // 0..79 (0..39 inst, 40..79 reid)
  const int rb  = xcd * 4 + (i & 3);   // 0..31
  const int tid = threadIdx.x;
  const int l = tid & 63;
  const int w = tid >> 6;
  const int wr = w >> 1, wc = w & 1;

  const bool inst = cb < 40;
  const int cbl = inst ? cb : cb - 40;

  // ---- prologue: rl_s + inst row-keys (latency hidden under K-loop) ----
  if (tid < 128) {
    int scol = cbl * 128 + tid;
    rl_s[tid] = (inst && scol < NPID) ? rlab[scol] : BIGVAL;
  }
  const int rlane = l & 15;
  const int rowb = rb * 128 + wr * 64 + rlane;
  int key[4];
#pragma unroll
  for (int nr = 0; nr < 4; ++nr)
    key[nr] = inst ? g[rowb + nr * 16] : BIGVAL;

  f32x4 acc[4][4];
#pragma unroll
  for (int mi = 0; mi < 4; ++mi)
#pragma unroll
    for (int ni = 0; ni < 4; ++ni) acc[mi][ni] = (f32x4){0.f, 0.f, 0.f, 0.f};

  // stage K-chunk t (32-wide) into buffer b: 16 frag-blocks, 4/wave.
  auto stage = [&](int t, int b) {
#pragma unroll
    for (int q = 0; q < 4; ++q) {
      const int f = w * 4 + q;           // 0..15
      const bool isA = f < 8;
      const int grp = f & 7;
      const int gidx = (isA ? rb * 8 : cb * 8) + grp;
      const _Float16* src = (isA ? Ap : Bp) + (((size_t)gidx * NCHUNK + t) << 9) + l * 8;
      unsigned short* dst = &lds[b * 8192 + (isA ? 0 : 4096) + grp * 512];
      __builtin_amdgcn_global_load_lds((const __attribute__((address_space(1))) unsigned int*)src,
                                       (__attribute__((address_space(3))) unsigned int*)dst,
                                       16, 0, 0);
    }
  };

  stage(0, 0);
  __syncthreads();                       // drain prologue stage + rl_s ordering
  int cur = 0;
#pragma unroll
  for (int t = 0; t < 8; ++t) {
    if (t < 7) stage(t + 1, cur ^ 1);    // issue-early: overlaps compute below
    half8 cf[4], rf[4];
#pragma unroll
    for (int mc = 0; mc < 4; ++mc)       // B frags
      cf[mc] = *(const half8*)&lds[cur * 8192 + 4096 + (wc * 4 + mc) * 512 + l * 8];
#pragma unroll
    for (int nr = 0; nr < 4; ++nr)       // A frags
      rf[nr] = *(const half8*)&lds[cur * 8192 + (wr * 4 + nr) * 512 + l * 8];
#pragma unroll
    for (int mc = 0; mc < 4; ++mc)
#pragma unroll
      for (int nr = 0; nr < 4; ++nr)
        acc[mc][nr] = __builtin_amdgcn_mfma_f32_16x16x32_f16(cf[mc], rf[nr], acc[mc][nr], 0, 0, 0);
    asm volatile("s_waitcnt vmcnt(0)" ::: "memory");  // next-tile loads landed
    asm volatile("s_barrier" ::: "memory");           // + all waves done reading cur
    cur ^= 1;
  }

  // ---- epilogue: unconditional exp2 sums (pads = +1 each, fixed in combine);
  //      inst side: positive exclusion via cndmask + rare posbuf branch ----
  const int colg = l >> 4;                  // 0..3
  const int chunk = (inst ? 0 : 80) + cbl * 2 + wc;
  const float NINF = -__builtin_inff();

  if (inst) {
    int4 rlv[4];
#pragma unroll
    for (int mc = 0; mc < 4; ++mc)          // broadcast reads, conflict-free
      rlv[mc] = *(const int4*)&rl_s[wc * 64 + mc * 16 + colg * 4];
#pragma unroll
    for (int nr = 0; nr < 4; ++nr) {
      const int row = rowb + nr * 16;
      const int kv = key[nr];
      float s = 0.f;
      int pmask = 0;
#pragma unroll
      for (int mc = 0; mc < 4; ++mc)
#pragma unroll
        for (int reg = 0; reg < 4; ++reg) {
          float x2 = acc[mc][nr][reg];       // already 30*log2e scaled
          int rl = ((const int*)&rlv[mc])[reg];
          bool pos = (rl == kv);
          pmask |= pos ? (1 << (mc * 4 + reg)) : 0;
          s += EXP2R(pos ? NINF : x2);       // exp2(-inf)=0
        }
      if (__builtin_expect(pmask != 0, 0)) {
#pragma unroll
        for (int mc = 0; mc < 4; ++mc)
#pragma unroll
          for (int reg = 0; reg < 4; ++reg)
            if (pmask & (1 << (mc * 4 + reg))) {
              int idx = atomicAdd(&poscnt[row], 1);
              if (idx < 16) posbuf[row * 16 + idx] = acc[mc][nr][reg];
            }
      }
      s += __shfl_xor(s, 16, 64);
      s += __shfl_xor(s, 32, 64);
      if (colg == 0) partials[(size_t)chunk * BT + row] = s;
    }
  } else {
#pragma unroll
    for (int nr = 0; nr < 4; ++nr) {
      const int row = rowb + nr * 16;
      float s = 0.f;
#pragma unroll
      for (int mc = 0; mc < 4; ++mc)
#pragma unroll
        for (int reg = 0; reg < 4; ++reg)
          s += EXP2R(acc[mc][nr][reg]);
      s += __shfl_xor(s, 16, 64);
      s += __shfl_xor(s, 32, 64);
      if (colg == 0) partials[(size_t)chunk * BT + row] = s;
    }
  }
}

// combine + finalize: per-row losses (pad-corrected sums), block-reduce,
// int64 fixed-point atomics (deterministic), last block writes out[0].
__global__ __launch_bounds__(256) void combine(const float* __restrict__ partials,
                                               const float* __restrict__ posbuf,
                                               const int* __restrict__ poscnt,
                                               const float* __restrict__ target,
                                               const float* __restrict__ w2f,
                                               const float* __restrict__ v1f,
                                               const float* __restrict__ fcv,
                                               unsigned long long* __restrict__ ctrl,
                                               float* __restrict__ out) {
  const int tid = threadIdx.x;
  const int row = blockIdx.x * 256 + tid;
  float S = 0.f;
  for (int i = 0; i < 80; ++i) S += partials[(size_t)i * BT + row];
  S -= NPAD;                                // remove exact pad contribution
  float lse2n = __log2f(S);                 // base-2 lse of negatives
  int cnt = poscnt[row];
  int cc = cnt < 16 ? cnt : 16;
  float sum = 0.f;
  for (int j = 0; j < cc; ++j) {
    float d = LN2 * (lse2n - posbuf[row * 16 + j]);
    sum += (d > 60.f) ? d : log1pf(__expf(d));
  }
  float w2 = w2f[row];
  float v[5];
  v[0] = fcv[row];
  v[1] = v1f[row];
  v[2] = w2;
  v[3] = w2 * (sum / fmaxf((float)cnt, 1.0f));
  float S2 = 0.f;
  for (int i = 80; i < 160; ++i) S2 += partials[(size_t)i * BT + row];
  S2 -= NPAD;
  v[4] = w2 * LN2 * (__log2f(S2) - target[row]);

#pragma unroll
  for (int k = 0; k < 5; ++k)
#pragma unroll
    for (int d = 1; d < 64; d <<= 1) v[k] += __shfl_xor(v[k], d, 64);
  __shared__ float red[4][5];
  int lane = tid & 63, wv = tid >> 6;
  if (lane == 0)
#pragma unroll
    for (int k = 0; k < 5; ++k) red[wv][k] = v[k];
  __syncthreads();
  if (tid == 0) {
#pragma unroll
    for (int k = 0; k < 5; ++k) {
      double bs = (double)red[0][k] + red[1][k] + red[2][k] + red[3][k];
      long long q = (long long)(bs * FXS + 0.5);
      atomicAdd(&ctrl[k], (unsigned long long)q);
    }
    __threadfence();
    unsigned int prev = atomicAdd((unsigned int*)&ctrl[6], 1u);
    if (prev == (unsigned int)(gridDim.x - 1)) {
      double a[5];
#pragma unroll
      for (int k = 0; k < 5; ++k)
        a[k] = (double)(long long)atomicAdd(&ctrl[k], 0ULL) / FXS;
      double n1 = a[1] > 1.0 ? a[1] : 1.0;
      double n2 = a[2] > 1.0 ? a[2] : 1.0;
      out[0] = (float)(a[0] / (n1 * (double)FDIM) + a[4] / n2 + a[3] / n2);
    }
  }
}

extern "C" void kernel_launch(void* const* d_in, const int* in_sizes, int n_in,
                              void* d_out, int out_size, void* d_ws, size_t ws_size,
                              hipStream_t stream) {
  const float* inputs = (const float*)d_in[0];
  const int*   roi    = (const int*)d_in[1];
  const float* lut    = (const float*)d_in[2];
  const float* reid   = (const float*)d_in[3];
  const int*   rlab   = (const int*)d_in[4];
  float* out = (float*)d_out;

  char* w = (char*)d_ws;
  _Float16* Ap    = (_Float16*)(w);                  // 2,097,152 B
  _Float16* Bp    = (_Float16*)(w + 2097152);        // 5,242,880 B  -> 7,340,032
  float* partials = (float*)(w + 7340032);           // 2,621,440 B  -> 9,961,472
  float* posbuf   = (float*)(w + 9961472);           // 262,144 B    -> 10,223,616
  int*   poscnt   = (int*)(w + 10223616);            // 16,384 B     -> 10,240,000
  float* target   = (float*)(w + 10240000);          // 16,384 B     -> 10,256,384
  int*   g        = (int*)(w + 10256384);            // 16,384 B     -> 10,272,768
  float* w2f      = (float*)(w + 10272768);          // 16,384 B     -> 10,289,152
  float* v1f      = (float*)(w + 10289152);          // 16,384 B     -> 10,305,536
  float* fcv      = (float*)(w + 10305536);          // 16,384 B     -> 10,321,920
  unsigned long long* ctrl = (unsigned long long*)(w + 10321920);  // 64 B

  prep<<<2320, 256, 0, stream>>>(inputs, roi, lut, reid, rlab, Ap, Bp,
                                 g, w2f, v1f, fcv, target, poscnt, ctrl);
  gemm_main<<<2560, 256, 0, stream>>>(Ap, Bp, rlab, g, partials, posbuf, poscnt);
  combine<<<BT / 256, 256, 0, stream>>>(partials, posbuf, poscnt, target,
                                        w2f, v1f, fcv, ctrl, out);
}